// Round 3
// baseline (605.478 us; speedup 1.0000x reference)
//
#include <hip/hip_runtime.h>
#include <hip/hip_cooperative_groups.h>
#include <stdint.h>

namespace cg = cooperative_groups;

// graph_smooth: x = node_features @ Emb; A[src,dst] = w (last write wins);
// out = A^3 @ x.  N=4096, E=131072, D_EMB=128, D_OUT=64, K=3.
//
// Single cooperative kernel: zero+embed | hash-insert | resolve+scatter |
// spmm x3, separated by grid.sync() (replaces 5 kernel-launch boundaries).

#define N_NODES 4096
#define D_EMB   128
#define D_OUT   64

#define HT_BITS 18
#define HT_SIZE (1u << HT_BITS)
#define HT_MASK (HT_SIZE - 1u)

#define CAP       128   // slots per row; Poisson(32) tail beyond 128 ~ 1e-40
#define CAP_SHIFT 7

#define NBLK  512
#define NTHR  256
#define NWAVE (NBLK * (NTHR / 64))   // 2048 waves

__device__ __forceinline__ uint32_t ht_hash(uint32_t key) {
    return (key * 2654435761u) >> (32 - HT_BITS);
}

__global__ void fused_kernel(const float* __restrict__ nf,
                             const float* __restrict__ emb,
                             const int* __restrict__ ei,
                             const float* __restrict__ ew,
                             int E,
                             float* __restrict__ out,
                             unsigned long long* __restrict__ table,
                             int* __restrict__ cnt,
                             int2* __restrict__ slots,
                             float* __restrict__ x0,
                             float* __restrict__ x1) {
    cg::grid_group grid = cg::this_grid();
    const int tid      = blockIdx.x * NTHR + threadIdx.x;   // 0 .. 131071
    const int nthreads = NBLK * NTHR;                        // 131072
    const int wave  = threadIdx.x >> 6;
    const int lane  = threadIdx.x & 63;
    const int gwave = blockIdx.x * (NTHR / 64) + wave;       // 0 .. 2047

    // ---------- phase A: zero table + cnt, x0 = nf @ Emb ----------
    {
        ulonglong2 z; z.x = 0ULL; z.y = 0ULL;
        ((ulonglong2*)table)[tid] = z;           // 131072 x 16B == HT_SIZE*8
        if (tid < N_NODES) cnt[tid] = 0;

        __shared__ float srow[NTHR / 64][D_EMB];
        for (int row = gwave; row < N_NODES; row += NWAVE) {  // exactly 2 iters, uniform
            srow[wave][lane]      = nf[row * D_EMB + lane];
            srow[wave][lane + 64] = nf[row * D_EMB + lane + 64];
            __syncthreads();
            float acc = 0.0f;
#pragma unroll 8
            for (int k = 0; k < D_EMB; ++k)
                acc = fmaf(srow[wave][k], emb[k * D_OUT + lane], acc);
            x0[row * D_OUT + lane] = acc;
            __syncthreads();
        }
    }
    __threadfence();
    grid.sync();

    // ---------- phase B: hash-insert; per (src,dst) keep MAX edge id ----------
    for (int e = tid; e < E; e += nthreads) {
        uint32_t src = (uint32_t)ei[e];
        uint32_t dst = (uint32_t)ei[E + e];
        uint32_t key = (src << 12) | dst;
        unsigned long long ent =
            ((unsigned long long)(key + 1u) << 32) | (uint32_t)e;
        uint32_t h = ht_hash(key) & HT_MASK;
        while (true) {
            unsigned long long cur = table[h];
            uint32_t ck = (uint32_t)(cur >> 32);
            if (ck == key + 1u) { atomicMax(&table[h], ent); break; }
            if (ck == 0u) {
                unsigned long long old = atomicCAS(&table[h], 0ULL, ent);
                if (old == 0ULL) break;
                if ((uint32_t)(old >> 32) == key + 1u) { atomicMax(&table[h], ent); break; }
            }
            h = (h + 1u) & HT_MASK;
        }
    }
    __threadfence();
    grid.sync();

    // ---------- phase C: resolve winners, scatter into row bins ----------
    for (int e = tid; e < E; e += nthreads) {
        uint32_t src = (uint32_t)ei[e];
        uint32_t dst = (uint32_t)ei[E + e];
        uint32_t key = (src << 12) | dst;
        uint32_t h = ht_hash(key) & HT_MASK;
        uint32_t win;
        while (true) {
            unsigned long long cur = table[h];
            if ((uint32_t)(cur >> 32) == key + 1u) { win = (uint32_t)cur; break; }
            h = (h + 1u) & HT_MASK;
        }
        if (win != (uint32_t)e) continue;   // duplicate loser -> weight 0 -> drop
        int idx = atomicAdd(&cnt[src], 1);
        if (idx < CAP) {
            int2 s;
            s.x = (int)dst;
            s.y = __float_as_int(ew[e]);
            slots[((int)src << CAP_SHIFT) + idx] = s;
        }
    }
    __threadfence();
    grid.sync();

    // ---------- phases D/E/F: three SpMM hops ----------
    auto spmm = [&](const float* __restrict__ x, float* __restrict__ y) {
        for (int row = gwave; row < N_NODES; row += NWAVE) {
            int c = cnt[row];
            if (c > CAP) c = CAP;
            const int2* s = slots + ((long)row << CAP_SHIFT);
            float acc = 0.0f;
            int i = 0;
            for (; i + 4 <= c; i += 4) {
                int2 s0 = s[i], s1 = s[i + 1], s2 = s[i + 2], s3 = s[i + 3];
                float v0 = x[s0.x * D_OUT + lane];
                float v1 = x[s1.x * D_OUT + lane];
                float v2 = x[s2.x * D_OUT + lane];
                float v3 = x[s3.x * D_OUT + lane];
                acc = fmaf(__int_as_float(s0.y), v0, acc);
                acc = fmaf(__int_as_float(s1.y), v1, acc);
                acc = fmaf(__int_as_float(s2.y), v2, acc);
                acc = fmaf(__int_as_float(s3.y), v3, acc);
            }
            for (; i < c; ++i) {
                int2 si = s[i];
                acc = fmaf(__int_as_float(si.y), x[si.x * D_OUT + lane], acc);
            }
            y[row * D_OUT + lane] = acc;
        }
    };

    spmm(x0, x1);
    __threadfence();
    grid.sync();

    spmm(x1, x0);
    __threadfence();
    grid.sync();

    spmm(x0, out);
}

extern "C" void kernel_launch(void* const* d_in, const int* in_sizes, int n_in,
                              void* d_out, int out_size, void* d_ws, size_t ws_size,
                              hipStream_t stream) {
    const float* nf  = (const float*)d_in[0];   // [N, 128]
    const float* emb = (const float*)d_in[1];   // [128, 64]
    const int*   ei  = (const int*)d_in[2];     // [2, E]
    const float* ew  = (const float*)d_in[3];   // [E]
    float* out = (float*)d_out;                 // [N, 64]

    int E = in_sizes[3];

    // ---- workspace carve-out (256B-aligned) ----
    char* ws = (char*)d_ws;
    size_t o = 0;
    auto take = [&](size_t bytes) -> void* {
        void* p = ws + o;
        o += (bytes + 255) & ~(size_t)255;
        return p;
    };
    unsigned long long* table = (unsigned long long*)take((size_t)HT_SIZE * 8);
    int*  cnt   = (int*)take((size_t)N_NODES * 4);
    int2* slots = (int2*)take((size_t)N_NODES * CAP * 8);
    float* x0   = (float*)take((size_t)N_NODES * D_OUT * 4);
    float* x1   = (float*)take((size_t)N_NODES * D_OUT * 4);

    void* args[] = {(void*)&nf, (void*)&emb, (void*)&ei, (void*)&ew, (void*)&E,
                    (void*)&out, (void*)&table, (void*)&cnt, (void*)&slots,
                    (void*)&x0, (void*)&x1};
    hipLaunchCooperativeKernel((const void*)fused_kernel, dim3(NBLK), dim3(NTHR),
                               args, 0, stream);
}

// Round 4
// 48.540 us; speedup vs baseline: 12.4739x; 12.4739x over previous
//
#include <hip/hip_runtime.h>
#include <stdint.h>

// graph_smooth: x = node_features @ Emb; A[src,dst] = w (last write wins);
// out = A^3 @ x.  N=4096, E=131072, D_EMB=128, D_OUT=64, K=3.
//
// Sparse, 5 dispatches, no hash table:
//   D1 embed (+zero cnt) | D2 scatter all edges into row bins (dst,w,eid) |
//   D3 per-row in-wave dedup (max eid wins) + hop1 | D4 hop2 | D5 hop3.
// Dedup inside the wave that owns the row: no global resolve pass needed;
// zeroed loser weights are written back so hops 2-3 see deduped bins.

#define N_NODES 4096
#define D_EMB   128
#define D_OUT   64

#define CAP       128   // slots per row incl. duplicates; Poisson(32) tail ~1e-40
#define CAP_SHIFT 7

// ---- D1: x0 = nf @ Emb (one wave per row) + zero cnt ----
__global__ void embed_kernel(const float* __restrict__ nf,
                             const float* __restrict__ emb,
                             float* __restrict__ x,
                             int* __restrict__ cnt) {
    int tid = blockIdx.x * blockDim.x + threadIdx.x;
    if (tid < N_NODES) cnt[tid] = 0;

    __shared__ float srow[4][D_EMB];
    int wave = threadIdx.x >> 6;
    int lane = threadIdx.x & 63;
    int row  = blockIdx.x * 4 + wave;          // 1024 blocks -> rows 0..4095
    srow[wave][lane]      = nf[row * D_EMB + lane];
    srow[wave][lane + 64] = nf[row * D_EMB + lane + 64];
    __syncthreads();
    float acc = 0.0f;
#pragma unroll 8
    for (int k = 0; k < D_EMB; ++k)
        acc = fmaf(srow[wave][k], emb[k * D_OUT + lane], acc);
    x[row * D_OUT + lane] = acc;
}

// ---- D2: scatter every edge (incl. duplicates) into its row bin ----
__global__ void scatter_kernel(const int* __restrict__ ei,
                               const float* __restrict__ ew, int E,
                               int* __restrict__ cnt,
                               int2* __restrict__ slots,    // {dst, w_bits}
                               int* __restrict__ eids) {
    int e = blockIdx.x * blockDim.x + threadIdx.x;
    if (e >= E) return;
    int src = ei[e];
    int dst = ei[E + e];
    int idx = atomicAdd(&cnt[src], 1);
    if (idx < CAP) {
        int2 s;
        s.x = dst;
        s.y = __float_as_int(ew[e]);
        int p = (src << CAP_SHIFT) + idx;
        slots[p] = s;
        eids[p]  = e;
    }
}

// ---- D3: per-row dedup (keep max eid per dst; numpy last-write-wins) + hop1
__global__ void dedup_spmm_kernel(const int* __restrict__ cnt,
                                  int2* __restrict__ slots,
                                  const int* __restrict__ eids,
                                  const float* __restrict__ x,
                                  float* __restrict__ y) {
    __shared__ int   sdst[4][CAP];
    __shared__ int   seid[4][CAP];
    __shared__ float sw[4][CAP];

    int wave = threadIdx.x >> 6;
    int lane = threadIdx.x & 63;
    int row  = blockIdx.x * 4 + wave;
    int c = cnt[row];
    if (c > CAP) c = CAP;
    int2* s = slots + ((long)row << CAP_SHIFT);
    const int* se = eids + ((long)row << CAP_SHIFT);

    // load bin into LDS (entries lane, lane+64)
#pragma unroll
    for (int half = 0; half < 2; ++half) {
        int i = lane + half * 64;
        if (i < c) {
            int2 si = s[i];
            sdst[wave][i] = si.x;
            sw[wave][i]   = __int_as_float(si.y);
            seid[wave][i] = se[i];
        }
    }
    __syncthreads();

    // dedup: entry i loses if some j has same dst and larger eid
#pragma unroll
    for (int half = 0; half < 2; ++half) {
        int i = lane + half * 64;
        if (i < c) {
            int d = sdst[wave][i], id = seid[wave][i];
            bool loser = false;
            for (int j = 0; j < c; ++j)
                loser |= (sdst[wave][j] == d) & (seid[wave][j] > id);
            if (loser) {
                sw[wave][i] = 0.0f;
                s[i].y = 0;          // make hops 2-3 see the dedup
            }
        }
    }
    __syncthreads();

    // hop 1: y[row,lane] = sum_i w_i * x[dst_i, lane]
    float acc = 0.0f;
    int i = 0;
    for (; i + 4 <= c; i += 4) {
        float v0 = x[sdst[wave][i]     * D_OUT + lane];
        float v1 = x[sdst[wave][i + 1] * D_OUT + lane];
        float v2 = x[sdst[wave][i + 2] * D_OUT + lane];
        float v3 = x[sdst[wave][i + 3] * D_OUT + lane];
        acc = fmaf(sw[wave][i],     v0, acc);
        acc = fmaf(sw[wave][i + 1], v1, acc);
        acc = fmaf(sw[wave][i + 2], v2, acc);
        acc = fmaf(sw[wave][i + 3], v3, acc);
    }
    for (; i < c; ++i)
        acc = fmaf(sw[wave][i], x[sdst[wave][i] * D_OUT + lane], acc);
    y[row * D_OUT + lane] = acc;
}

// ---- D4/D5: plain SpMM hop, one wave per row ----
__global__ void spmm_kernel(const int* __restrict__ cnt,
                            const int2* __restrict__ slots,
                            const float* __restrict__ x,
                            float* __restrict__ y) {
    int wave = threadIdx.x >> 6;
    int lane = threadIdx.x & 63;
    int row  = blockIdx.x * 4 + wave;
    int c = cnt[row];
    if (c > CAP) c = CAP;
    const int2* s = slots + ((long)row << CAP_SHIFT);
    float acc = 0.0f;
    int i = 0;
    for (; i + 4 <= c; i += 4) {
        int2 s0 = s[i], s1 = s[i + 1], s2 = s[i + 2], s3 = s[i + 3];
        float v0 = x[s0.x * D_OUT + lane];
        float v1 = x[s1.x * D_OUT + lane];
        float v2 = x[s2.x * D_OUT + lane];
        float v3 = x[s3.x * D_OUT + lane];
        acc = fmaf(__int_as_float(s0.y), v0, acc);
        acc = fmaf(__int_as_float(s1.y), v1, acc);
        acc = fmaf(__int_as_float(s2.y), v2, acc);
        acc = fmaf(__int_as_float(s3.y), v3, acc);
    }
    for (; i < c; ++i) {
        int2 si = s[i];
        acc = fmaf(__int_as_float(si.y), x[si.x * D_OUT + lane], acc);
    }
    y[row * D_OUT + lane] = acc;
}

extern "C" void kernel_launch(void* const* d_in, const int* in_sizes, int n_in,
                              void* d_out, int out_size, void* d_ws, size_t ws_size,
                              hipStream_t stream) {
    const float* nf  = (const float*)d_in[0];   // [N, 128]
    const float* emb = (const float*)d_in[1];   // [128, 64]
    const int*   ei  = (const int*)d_in[2];     // [2, E]
    const float* ew  = (const float*)d_in[3];   // [E]
    float* out = (float*)d_out;                 // [N, 64]

    const int E = in_sizes[3];

    // ---- workspace carve-out (256B-aligned) ----
    char* ws = (char*)d_ws;
    size_t o = 0;
    auto take = [&](size_t bytes) -> void* {
        void* p = ws + o;
        o += (bytes + 255) & ~(size_t)255;
        return p;
    };
    int*  cnt   = (int*)take((size_t)N_NODES * 4);
    int2* slots = (int2*)take((size_t)N_NODES * CAP * 8);
    int*  eids  = (int*)take((size_t)N_NODES * CAP * 4);
    float* x0   = (float*)take((size_t)N_NODES * D_OUT * 4);
    float* x1   = (float*)take((size_t)N_NODES * D_OUT * 4);

    const int TB = 256;
    const int EB = (E + TB - 1) / TB;         // 512
    const int NB = N_NODES / 4;               // 1024 (4 waves/block, 1 row/wave)

    embed_kernel<<<NB, TB, 0, stream>>>(nf, emb, x0, cnt);
    scatter_kernel<<<EB, TB, 0, stream>>>(ei, ew, E, cnt, slots, eids);
    dedup_spmm_kernel<<<NB, TB, 0, stream>>>(cnt, slots, eids, x0, x1);
    spmm_kernel<<<NB, TB, 0, stream>>>(cnt, slots, x1, x0);
    spmm_kernel<<<NB, TB, 0, stream>>>(cnt, slots, x0, out);
}

// Round 5
// 44.668 us; speedup vs baseline: 13.5550x; 1.0867x over previous
//
#include <hip/hip_runtime.h>
#include <stdint.h>

// graph_smooth: x = node_features @ Emb; A[src,dst] = w (last write wins);
// out = A^3 @ x.  N=4096, E=131072, D_EMB=128, D_OUT=64, K=3.
//
// Launch-bound pipeline -> minimize graph nodes:
//   N0 memset(cnt,16KB) | N1 fused embed+scatter | N2 dedup+hop1 |
//   N3 hop2 | N4 hop3.
// Bins are int4 {dst, w_bits, eid, pad}; dedup (numpy last-write-wins = max
// eid per (src,dst)) runs in the wave that owns the row during hop1 and
// writes w=0 back for losers so hops 2-3 see deduped bins.

#define N_NODES 4096
#define D_EMB   128
#define D_OUT   64

#define CAP       128   // slots per row incl. duplicates; Poisson(32) tail ~1e-40
#define CAP_SHIFT 7

// ---- N1: blocks 0..1023 embed (4 waves x 1 row), blocks 1024..1535 scatter.
__global__ void embed_scatter_kernel(const float* __restrict__ nf,
                                     const float* __restrict__ emb,
                                     float* __restrict__ x,
                                     const int* __restrict__ ei,
                                     const float* __restrict__ ew, int E,
                                     int* __restrict__ cnt,
                                     int4* __restrict__ slots) {
    if (blockIdx.x < 1024) {
        // ---- embed: x[row,:] = nf[row,:] @ emb ----
        __shared__ float srow[4][D_EMB];
        int wave = threadIdx.x >> 6;
        int lane = threadIdx.x & 63;
        int row  = blockIdx.x * 4 + wave;
        float2 a = ((const float2*)(nf + (size_t)row * D_EMB))[lane];
        srow[wave][2 * lane]     = a.x;
        srow[wave][2 * lane + 1] = a.y;
        __syncthreads();
        float acc = 0.0f;
#pragma unroll 8
        for (int k = 0; k < D_EMB; ++k)
            acc = fmaf(srow[wave][k], emb[k * D_OUT + lane], acc);
        x[row * D_OUT + lane] = acc;
    } else {
        // ---- scatter: bin every edge (incl. duplicates) by src ----
        int e = (blockIdx.x - 1024) * blockDim.x + threadIdx.x;
        if (e >= E) return;
        int src = ei[e];
        int dst = ei[E + e];
        int idx = atomicAdd(&cnt[src], 1);
        if (idx < CAP) {
            int4 s;
            s.x = dst;
            s.y = __float_as_int(ew[e]);
            s.z = e;
            s.w = 0;
            slots[(src << CAP_SHIFT) + idx] = s;
        }
    }
}

// ---- N2: per-row dedup (keep max eid per dst) + hop1; one wave per row ----
__global__ void dedup_spmm_kernel(const int* __restrict__ cnt,
                                  int4* __restrict__ slots,
                                  const float* __restrict__ x,
                                  float* __restrict__ y) {
    __shared__ int   sdst[4][CAP];
    __shared__ int   seid[4][CAP];
    __shared__ float sw[4][CAP];

    int wave = threadIdx.x >> 6;
    int lane = threadIdx.x & 63;
    int row  = blockIdx.x * 4 + wave;
    int c = cnt[row];
    if (c > CAP) c = CAP;
    int4* s = slots + ((long)row << CAP_SHIFT);

#pragma unroll
    for (int half = 0; half < 2; ++half) {
        int i = lane + half * 64;
        if (i < c) {
            int4 si = s[i];
            sdst[wave][i] = si.x;
            sw[wave][i]   = __int_as_float(si.y);
            seid[wave][i] = si.z;
        }
    }
    __syncthreads();

    // dedup: entry i loses if some j has same dst and larger eid
#pragma unroll
    for (int half = 0; half < 2; ++half) {
        int i = lane + half * 64;
        if (i < c) {
            int d = sdst[wave][i], id = seid[wave][i];
            bool loser = false;
            for (int j = 0; j < c; ++j)
                loser |= (sdst[wave][j] == d) & (seid[wave][j] > id);
            if (loser) {
                sw[wave][i] = 0.0f;
                ((int*)&s[i])[1] = 0;   // write w=0 back for hops 2-3
            }
        }
    }
    __syncthreads();

    // hop 1, 8-deep gather ILP
    float acc = 0.0f;
    int i = 0;
    for (; i + 8 <= c; i += 8) {
        float vw[8], vx[8];
#pragma unroll
        for (int k = 0; k < 8; ++k) vw[k] = sw[wave][i + k];
        int vd[8];
#pragma unroll
        for (int k = 0; k < 8; ++k) vd[k] = sdst[wave][i + k];
#pragma unroll
        for (int k = 0; k < 8; ++k) vx[k] = x[vd[k] * D_OUT + lane];
#pragma unroll
        for (int k = 0; k < 8; ++k) acc = fmaf(vw[k], vx[k], acc);
    }
    for (; i < c; ++i)
        acc = fmaf(sw[wave][i], x[sdst[wave][i] * D_OUT + lane], acc);
    y[row * D_OUT + lane] = acc;
}

// ---- N3/N4: plain SpMM hop with LDS-staged bins; one wave per row ----
__global__ void spmm_kernel(const int* __restrict__ cnt,
                            const int4* __restrict__ slots,
                            const float* __restrict__ x,
                            float* __restrict__ y) {
    __shared__ int   sdst[4][CAP];
    __shared__ float sw[4][CAP];

    int wave = threadIdx.x >> 6;
    int lane = threadIdx.x & 63;
    int row  = blockIdx.x * 4 + wave;
    int c = cnt[row];
    if (c > CAP) c = CAP;
    const int4* s = slots + ((long)row << CAP_SHIFT);

#pragma unroll
    for (int half = 0; half < 2; ++half) {
        int i = lane + half * 64;
        if (i < c) {
            int4 si = s[i];
            sdst[wave][i] = si.x;
            sw[wave][i]   = __int_as_float(si.y);
        }
    }
    __syncthreads();

    float acc = 0.0f;
    int i = 0;
    for (; i + 8 <= c; i += 8) {
        float vw[8], vx[8];
#pragma unroll
        for (int k = 0; k < 8; ++k) vw[k] = sw[wave][i + k];
        int vd[8];
#pragma unroll
        for (int k = 0; k < 8; ++k) vd[k] = sdst[wave][i + k];
#pragma unroll
        for (int k = 0; k < 8; ++k) vx[k] = x[vd[k] * D_OUT + lane];
#pragma unroll
        for (int k = 0; k < 8; ++k) acc = fmaf(vw[k], vx[k], acc);
    }
    for (; i < c; ++i)
        acc = fmaf(sw[wave][i], x[sdst[wave][i] * D_OUT + lane], acc);
    y[row * D_OUT + lane] = acc;
}

extern "C" void kernel_launch(void* const* d_in, const int* in_sizes, int n_in,
                              void* d_out, int out_size, void* d_ws, size_t ws_size,
                              hipStream_t stream) {
    const float* nf  = (const float*)d_in[0];   // [N, 128]
    const float* emb = (const float*)d_in[1];   // [128, 64]
    const int*   ei  = (const int*)d_in[2];     // [2, E]
    const float* ew  = (const float*)d_in[3];   // [E]
    float* out = (float*)d_out;                 // [N, 64]

    const int E = in_sizes[3];

    // ---- workspace carve-out (256B-aligned) ----
    char* ws = (char*)d_ws;
    size_t o = 0;
    auto take = [&](size_t bytes) -> void* {
        void* p = ws + o;
        o += (bytes + 255) & ~(size_t)255;
        return p;
    };
    int*  cnt   = (int*)take((size_t)N_NODES * 4);
    int4* slots = (int4*)take((size_t)N_NODES * CAP * 16);
    float* x0   = (float*)take((size_t)N_NODES * D_OUT * 4);
    float* x1   = (float*)take((size_t)N_NODES * D_OUT * 4);

    const int TB = 256;
    const int NB = N_NODES / 4;                       // 1024
    const int SB = (E + TB - 1) / TB;                 // 512

    hipMemsetAsync(cnt, 0, (size_t)N_NODES * 4, stream);            // N0
    embed_scatter_kernel<<<NB + SB, TB, 0, stream>>>(nf, emb, x0,   // N1
                                                     ei, ew, E, cnt, slots);
    dedup_spmm_kernel<<<NB, TB, 0, stream>>>(cnt, slots, x0, x1);   // N2
    spmm_kernel<<<NB, TB, 0, stream>>>(cnt, slots, x1, x0);         // N3
    spmm_kernel<<<NB, TB, 0, stream>>>(cnt, slots, x0, out);        // N4
}